// Round 4
// baseline (2707.029 us; speedup 1.0000x reference)
//
#include <hip/hip_runtime.h>

typedef _Float16 half_t;
typedef _Float16 half8  __attribute__((ext_vector_type(8)));
typedef float    f32x4  __attribute__((ext_vector_type(4)));
typedef int      i32x4  __attribute__((ext_vector_type(4)));

#define NB 64
#define NT 256
#define NI 1024
#define NH 512

// ---- cache-bypassing (MALL-coherent) 16B load/store ----
__device__ __forceinline__ void gload16_cc(i32x4& v, const void* p) {
    asm volatile("global_load_dwordx4 %0, %1, off sc0 sc1"
                 : "=v"(v) : "v"(p) : "memory");
}
__device__ __forceinline__ void gstore16_cc(void* p, i32x4 v) {
    asm volatile("global_store_dwordx4 %0, %1, off sc0 sc1"
                 :: "v"(p), "v"(v) : "memory");
}

// ---------------- flag-array group barrier ----------------
// slots[i] = generation WG i has arrived at (monotone). Wave 0 drains its own
// global stores, leader stores its slot, all lanes poll all slots wave-wide.
__device__ __forceinline__ void flag_barrier(unsigned* slots, int nslots,
                                             int my, unsigned gen, int tid) {
    if (tid < 64) {
        asm volatile("s_waitcnt vmcnt(0)" ::: "memory");   // h stores visible first
        if (tid == 0) {
            unsigned gv = gen;
            asm volatile("global_store_dword %0, %1, off sc0 sc1"
                         :: "v"(slots + my), "v"(gv) : "memory");
        }
        const unsigned* p = slots + (tid & (nslots - 1));
        int guard = 0;
        while (true) {
            unsigned v;
            asm volatile("global_load_dword %0, %1, off sc0 sc1"
                         : "=v"(v) : "v"(p) : "memory");
            asm volatile("s_waitcnt vmcnt(0)" ::: "memory");
            if (__all(v >= gen)) break;
            __builtin_amdgcn_s_sleep(1);
            if (++guard > (1 << 22)) break;   // failsafe: wrong beats hang
        }
    }
    __syncthreads();
}

// ---------------- fp32 -> fp16 convert ----------------
__global__ __launch_bounds__(256) void k_cvt(const float* __restrict__ s,
                                             half_t* __restrict__ d, int n4) {
    int i = blockIdx.x * 256 + threadIdx.x;
    if (i < n4) {
        float4 v = reinterpret_cast<const float4*>(s)[i];
        half_t h4[4] = {(half_t)v.x, (half_t)v.y, (half_t)v.z, (half_t)v.w};
        *reinterpret_cast<long*>(&d[i * 4]) = *reinterpret_cast<long*>(h4);
    }
}

// ---------------- GEMM: C[M,N](f16) = A[M,K] * Bw[N,K]^T + bias ----------------
// A is fp32 (AF32) converted during staging, or fp16. C row stride = ldc.
template <int K, bool AF32>
__global__ __launch_bounds__(256) void k_gemm(const void* __restrict__ Av,
                                              const half_t* __restrict__ Bw,
                                              const float* __restrict__ bias,
                                              half_t* __restrict__ C, int N, int ldc) {
    constexpr int BK = 64;
    __shared__ half_t Al[2][128 * BK] __attribute__((aligned(16)));
    __shared__ half_t Bl[2][128 * BK] __attribute__((aligned(16)));

    const int tid = threadIdx.x, lane = tid & 63, wv = tid >> 6;
    const long m0 = (long)blockIdx.y * 128;
    const long n0 = (long)blockIdx.x * 128;
    const int wm = (wv >> 1) * 64, wn = (wv & 1) * 64;

    f32x4 acc[4][4];
#pragma unroll
    for (int nt = 0; nt < 4; ++nt) {
        float bv = bias[n0 + wn + nt * 16 + (lane & 15)];
#pragma unroll
        for (int mt = 0; mt < 4; ++mt) acc[mt][nt] = (f32x4){bv, bv, bv, bv};
    }

    auto stage = [&](int buf, int kt) {
#pragma unroll
        for (int j = 0; j < 4; ++j) {
            int c = tid + 256 * j;
            int row = c >> 3, cin = c & 7;
            int dst = row * BK + ((cin ^ (row & 7)) << 3);
            if constexpr (AF32) {
                const float* Af = (const float*)Av;
                const float* src = Af + (m0 + row) * K + kt * BK + cin * 8;
                float4 f0 = *reinterpret_cast<const float4*>(src);
                float4 f1 = *reinterpret_cast<const float4*>(src + 4);
                half8 h;
                h[0] = (half_t)f0.x; h[1] = (half_t)f0.y; h[2] = (half_t)f0.z; h[3] = (half_t)f0.w;
                h[4] = (half_t)f1.x; h[5] = (half_t)f1.y; h[6] = (half_t)f1.z; h[7] = (half_t)f1.w;
                *reinterpret_cast<half8*>(&Al[buf][dst]) = h;
            } else {
                const half_t* Ah = (const half_t*)Av;
                *reinterpret_cast<int4*>(&Al[buf][dst]) =
                    *reinterpret_cast<const int4*>(Ah + (m0 + row) * K + kt * BK + cin * 8);
            }
            *reinterpret_cast<int4*>(&Bl[buf][dst]) =
                *reinterpret_cast<const int4*>(Bw + (n0 + row) * K + kt * BK + cin * 8);
        }
    };

    stage(0, 0);
    __syncthreads();
    constexpr int NK = K / BK;
    int buf = 0;
    for (int kt = 0; kt < NK; ++kt) {
        if (kt + 1 < NK) stage(buf ^ 1, kt + 1);
        half8 af[4][2], bf[4][2];
#pragma unroll
        for (int mt = 0; mt < 4; ++mt)
#pragma unroll
            for (int ks = 0; ks < 2; ++ks) {
                int lr = wm + mt * 16 + (lane & 15);
                int off = lr * BK + ((ks * 32 + 8 * (lane >> 4)) ^ ((lr & 7) << 3));
                af[mt][ks] = *reinterpret_cast<const half8*>(&Al[buf][off]);
            }
#pragma unroll
        for (int nt = 0; nt < 4; ++nt)
#pragma unroll
            for (int ks = 0; ks < 2; ++ks) {
                int lr = wn + nt * 16 + (lane & 15);
                int off = lr * BK + ((ks * 32 + 8 * (lane >> 4)) ^ ((lr & 7) << 3));
                bf[nt][ks] = *reinterpret_cast<const half8*>(&Bl[buf][off]);
            }
#pragma unroll
        for (int mt = 0; mt < 4; ++mt)
#pragma unroll
            for (int nt = 0; nt < 4; ++nt)
#pragma unroll
                for (int ks = 0; ks < 2; ++ks)
                    acc[mt][nt] = __builtin_amdgcn_mfma_f32_16x16x32_f16(
                        af[mt][ks], bf[nt][ks], acc[mt][nt], 0, 0, 0);
        __syncthreads();
        buf ^= 1;
    }
#pragma unroll
    for (int mt = 0; mt < 4; ++mt)
#pragma unroll
        for (int nt = 0; nt < 4; ++nt)
#pragma unroll
            for (int i = 0; i < 4; ++i) {
                long row = m0 + wm + mt * 16 + 4 * (lane >> 4) + i;
                long col = n0 + wn + nt * 16 + (lane & 15);
                C[row * (long)ldc + col] = (half_t)acc[mt][nt][i];
            }
}

#define XCH(gt, bb, ee) xch[((gt) * 8 + (bb)) * 16 + (ee)]

// ---------------- Phase 1 (fused): layer-1 recurrence + on-the-fly gemm2 ----
// 8 groups x 32 WGs; group g owns batches [8g,8g+8). WG owns 16 h-elems for the
// gates AND 96 rows of w_ih2 for gx2. At loop t, LDS h-tile = h_{t-1}; wave 3
// computes gx2[:, t-1, :] slice = relu(h_{t-1}) @ w_ih2^T + b_ih2 (hidden under
// the gate/barrier latency). gx (layer-1 input proj) and gx2 alias one buffer
// with row stride 3072: gx1 row t is dead before gx2 row t-1 is written.
__global__ __launch_bounds__(256, 1) void k_phase1(const half_t* __restrict__ whh,
                                                   const float* __restrict__ bhh,
                                                   const half_t* gx,
                                                   const half_t* __restrict__ wih2,
                                                   const float* __restrict__ bih2,
                                                   half_t* gx2,
                                                   half_t* __restrict__ hf16,
                                                   unsigned* __restrict__ slots) {
    // 160 KiB arena, hand-placed: [0,48K) gate W | [48K,144K) w_ih2 slice |
    // [144K,160K) h-tile (16 rows; rows 8-15 are garbage-tolerated MFMA pad,
    // their space hosts xch + hstore).
    __shared__ __attribute__((aligned(16))) char arena[163840];
    half_t* wl  = (half_t*)arena;                       // 48 x 512
    half_t* wl2 = (half_t*)(arena + 49152);             // 96 x 512
    half_t* hl  = (half_t*)(arena + 147456);            // 16 x 512 (rows 0-7 real)
    float*  xch = (float*)(arena + 147456 + 8192);      // [3][8][16]
    half_t* hst = (half_t*)(arena + 147456 + 8192 + 1536);  // [8][16]

    const int tid = threadIdx.x, lane = tid & 63, wv = tid >> 6;
    const int g = blockIdx.x & 7, memb = blockIdx.x >> 3;
    const int e0 = memb * 16;
    unsigned* gslots = slots + g * 64;

    // gate weights: local row lr = 16*gate + e -> global row gate*512 + e0 + e
#pragma unroll
    for (int j = 0; j < 12; ++j) {
        int c = tid + 256 * j;                 // 3072 chunks
        int lr = c >> 6, cin = c & 63;
        int grow = (lr >> 4) * NH + e0 + (lr & 15);
        int dst = lr * NH + ((cin ^ (lr & 7)) << 3);
        *reinterpret_cast<int4*>(&wl[dst]) =
            *reinterpret_cast<const int4*>(whh + (long)grow * NH + cin * 8);
    }
    // w_ih2 slice: rows [memb*96, memb*96+96)
#pragma unroll
    for (int j = 0; j < 24; ++j) {
        int c = tid + 256 * j;                 // 6144 chunks
        int lr = c >> 6, cin = c & 63;
        int dst = lr * NH + ((cin ^ (lr & 7)) << 3);
        *reinterpret_cast<int4*>(&wl2[dst]) =
            *reinterpret_cast<const int4*>(wih2 + (long)(memb * 96 + lr) * NH + cin * 8);
    }
    if (tid < 16) {
        i32x4 z = (i32x4){0, 0, 0, 0};
        int bb = tid >> 1, seg = tid & 1;
        gstore16_cc(hf16 + (g * 8 + bb) * NH + e0 + seg * 8, z);
    }
    float hp = 0.f;
    __syncthreads();
    flag_barrier(gslots, 32, memb, 1, tid);

    const float bgate = (wv < 3) ? bhh[wv * NH + e0 + (lane & 15)] : 0.f;
    float bg2[6];
    if (wv == 3) {
#pragma unroll
        for (int nt2 = 0; nt2 < 6; ++nt2)
            bg2[nt2] = bih2[memb * 96 + nt2 * 16 + (lane & 15)];
    }
    const int b = tid >> 4, e = tid & 15;
    const long rb0 = (long)(g * 8 + b) * NT;

    float xr = 0.f, xz = 0.f, xn = 0.f, nxr = 0.f, nxz = 0.f, nxn = 0.f;
    if (tid < 128) {                           // gx for t=0
        long gb = rb0 * 3072 + e0 + e;
        xr = (float)gx[gb]; xz = (float)gx[gb + NH]; xn = (float)gx[gb + 2 * NH];
    }

    for (int t = 0; t < NT; ++t) {
        const half_t* hsrc = hf16 + (t & 1) * (NB * NH);
        i32x4 sv[2];
#pragma unroll
        for (int j = 0; j < 2; ++j) {
            int c = tid + 256 * j;             // 512 chunks
            int lr = c >> 6, cin = c & 63;
            gload16_cc(sv[j], hsrc + (g * 8 + lr) * NH + cin * 8);
        }
        asm volatile("s_waitcnt vmcnt(0)" ::: "memory");
#pragma unroll
        for (int j = 0; j < 2; ++j) {
            int c = tid + 256 * j;
            int lr = c >> 6, cin = c & 63;
            *reinterpret_cast<i32x4*>(&hl[lr * NH + ((cin ^ (lr & 7)) << 3)]) = sv[j];
        }
        __syncthreads();

        // prefetch next step's gx (hidden under MFMA + barrier)
        if (tid < 128 && t + 1 < NT) {
            long gb = (rb0 + t + 1) * 3072 + e0 + e;
            nxr = (float)gx[gb]; nxz = (float)gx[gb + NH]; nxn = (float)gx[gb + 2 * NH];
        }

        if (wv < 3) {                          // gates
            f32x4 a0 = (f32x4){bgate, bgate, bgate, bgate};
            f32x4 a1 = (f32x4){0.f, 0.f, 0.f, 0.f};
#pragma unroll
            for (int ks = 0; ks < 16; ks += 2) {
                int ar = lane & 15;
                int br = wv * 16 + (lane & 15);
                int ao0 = ar * NH + ((ks * 32 + 8 * (lane >> 4)) ^ ((ar & 7) << 3));
                int bo0 = br * NH + ((ks * 32 + 8 * (lane >> 4)) ^ ((br & 7) << 3));
                int ao1 = ar * NH + (((ks + 1) * 32 + 8 * (lane >> 4)) ^ ((ar & 7) << 3));
                int bo1 = br * NH + (((ks + 1) * 32 + 8 * (lane >> 4)) ^ ((br & 7) << 3));
                a0 = __builtin_amdgcn_mfma_f32_16x16x32_f16(
                    *reinterpret_cast<const half8*>(&hl[ao0]),
                    *reinterpret_cast<const half8*>(&wl[bo0]), a0, 0, 0, 0);
                a1 = __builtin_amdgcn_mfma_f32_16x16x32_f16(
                    *reinterpret_cast<const half8*>(&hl[ao1]),
                    *reinterpret_cast<const half8*>(&wl[bo1]), a1, 0, 0, 0);
            }
            f32x4 acc = a0 + a1;
            if (lane < 32) {
#pragma unroll
                for (int i = 0; i < 4; ++i)
                    XCH(wv, 4 * (lane >> 4) + i, lane & 15) = acc[i];
            }
        } else if (t > 0) {                    // wave 3: gx2 for timestep t-1
            f32x4 g2[6];
#pragma unroll
            for (int nt2 = 0; nt2 < 6; ++nt2)
                g2[nt2] = (f32x4){bg2[nt2], bg2[nt2], bg2[nt2], bg2[nt2]};
#pragma unroll
            for (int ks = 0; ks < 16; ++ks) {
                int ar = lane & 15;
                int ao = ar * NH + ((ks * 32 + 8 * (lane >> 4)) ^ ((ar & 7) << 3));
                half8 a = *reinterpret_cast<const half8*>(&hl[ao]);
#pragma unroll
                for (int j2 = 0; j2 < 8; ++j2)
                    a[j2] = a[j2] > (half_t)0.f ? a[j2] : (half_t)0.f;   // relu
#pragma unroll
                for (int nt2 = 0; nt2 < 6; ++nt2) {
                    int br2 = nt2 * 16 + (lane & 15);
                    int bo = br2 * NH + ((ks * 32 + 8 * (lane >> 4)) ^ ((br2 & 7) << 3));
                    g2[nt2] = __builtin_amdgcn_mfma_f32_16x16x32_f16(
                        a, *reinterpret_cast<const half8*>(&wl2[bo]), g2[nt2], 0, 0, 0);
                }
            }
            if (lane < 32) {
                int r0 = 4 * (lane >> 4);
#pragma unroll
                for (int nt2 = 0; nt2 < 6; ++nt2)
#pragma unroll
                    for (int i = 0; i < 4; ++i) {
                        long bb = g * 8 + r0 + i;
                        gx2[(bb * NT + (t - 1)) * 3072 + memb * 96 + nt2 * 16 + (lane & 15)] =
                            (half_t)g2[nt2][i];
                    }
            }
        }
        __syncthreads();

        if (tid < 128) {                       // gate combine
            float r = 1.f / (1.f + __expf(-(xr + XCH(0, b, e))));
            float z = 1.f / (1.f + __expf(-(xz + XCH(1, b, e))));
            float n = tanhf(xn + r * XCH(2, b, e));
            float hn = (1.f - z) * n + z * hp;
            hp = hn;
            hst[b * 16 + e] = (half_t)hn;
        }
        __syncthreads();

        if (tid < 16) {
            int bb = tid >> 1, seg = tid & 1;
            i32x4 v = *reinterpret_cast<const i32x4*>(&hst[bb * 16 + seg * 8]);
            gstore16_cc(hf16 + ((t + 1) & 1) * (NB * NH) + (g * 8 + bb) * NH + e0 + seg * 8, v);
        }
        flag_barrier(gslots, 32, memb, t + 2, tid);
        xr = nxr; xz = nxz; xn = nxn;
    }

    // epilogue: gx2 for the final timestep NT-1 (h stored in buffer (NT&1)=0)
    {
        const half_t* hsrc = hf16 + (NT & 1) * (NB * NH);
        i32x4 sv[2];
#pragma unroll
        for (int j = 0; j < 2; ++j) {
            int c = tid + 256 * j;
            int lr = c >> 6, cin = c & 63;
            gload16_cc(sv[j], hsrc + (g * 8 + lr) * NH + cin * 8);
        }
        asm volatile("s_waitcnt vmcnt(0)" ::: "memory");
#pragma unroll
        for (int j = 0; j < 2; ++j) {
            int c = tid + 256 * j;
            int lr = c >> 6, cin = c & 63;
            *reinterpret_cast<i32x4*>(&hl[lr * NH + ((cin ^ (lr & 7)) << 3)]) = sv[j];
        }
        __syncthreads();
        if (wv == 3) {
            f32x4 g2[6];
#pragma unroll
            for (int nt2 = 0; nt2 < 6; ++nt2)
                g2[nt2] = (f32x4){bg2[nt2], bg2[nt2], bg2[nt2], bg2[nt2]};
#pragma unroll
            for (int ks = 0; ks < 16; ++ks) {
                int ar = lane & 15;
                int ao = ar * NH + ((ks * 32 + 8 * (lane >> 4)) ^ ((ar & 7) << 3));
                half8 a = *reinterpret_cast<const half8*>(&hl[ao]);
#pragma unroll
                for (int j2 = 0; j2 < 8; ++j2)
                    a[j2] = a[j2] > (half_t)0.f ? a[j2] : (half_t)0.f;
#pragma unroll
                for (int nt2 = 0; nt2 < 6; ++nt2) {
                    int br2 = nt2 * 16 + (lane & 15);
                    int bo = br2 * NH + ((ks * 32 + 8 * (lane >> 4)) ^ ((br2 & 7) << 3));
                    g2[nt2] = __builtin_amdgcn_mfma_f32_16x16x32_f16(
                        a, *reinterpret_cast<const half8*>(&wl2[bo]), g2[nt2], 0, 0, 0);
                }
            }
            if (lane < 32) {
                int r0 = 4 * (lane >> 4);
#pragma unroll
                for (int nt2 = 0; nt2 < 6; ++nt2)
#pragma unroll
                    for (int i = 0; i < 4; ++i) {
                        long bb = g * 8 + r0 + i;
                        gx2[(bb * NT + (NT - 1)) * 3072 + memb * 96 + nt2 * 16 + (lane & 15)] =
                            (half_t)g2[nt2][i];
                    }
            }
        }
    }
}

// ---------------- Phase 2: layer-2 recurrence (persistent) ----------------
// 4 groups x 64 WGs; group g owns batches [16g,16g+16). WG owns 16 out-elems.
// gx prefetched one step ahead; out-store issued after the flag store.
__global__ __launch_bounds__(256, 1) void k_phase2(const half_t* __restrict__ whh,
                                                   const float* __restrict__ bhh,
                                                   const half_t* __restrict__ gx,
                                                   float* __restrict__ out,
                                                   half_t* __restrict__ hf16,
                                                   unsigned* __restrict__ slots) {
    __shared__ half_t wl[48 * NI] __attribute__((aligned(16)));   // 96KB
    __shared__ half_t hl[16 * NI] __attribute__((aligned(16)));   // 32KB
    __shared__ float xch2[3][16][16];
    __shared__ half_t hst[16][16] __attribute__((aligned(16)));

    const int tid = threadIdx.x, lane = tid & 63, wv = tid >> 6;
    const int xcd = blockIdx.x & 7;
    const int g = xcd >> 1;
    const int memb = ((blockIdx.x >> 3) << 1) | (xcd & 1);  // 0..63
    const int e0 = memb * 16;
    unsigned* gslots = slots + g * 64;

#pragma unroll
    for (int j = 0; j < 24; ++j) {
        int c = tid + 256 * j;                 // 6144 chunks
        int lr = c >> 7, cin = c & 127;
        int grow = (lr >> 4) * NI + e0 + (lr & 15);
        int dst = lr * NI + ((cin ^ (lr & 7)) << 3);
        *reinterpret_cast<int4*>(&wl[dst]) =
            *reinterpret_cast<const int4*>(whh + (long)grow * NI + cin * 8);
    }
    if (tid < 32) {
        i32x4 z = (i32x4){0, 0, 0, 0};
        int bb = tid >> 1, seg = tid & 1;
        gstore16_cc(hf16 + (g * 16 + bb) * NI + e0 + seg * 8, z);
    }
    float hp = 0.f;
    __syncthreads();
    flag_barrier(gslots, 64, memb, 1, tid);

    const float bgate = (wv < 3) ? bhh[wv * NI + e0 + (lane & 15)] : 0.f;
    const int b = tid >> 4, e = tid & 15;
    const long rb0 = (long)(g * 16 + b) * NT;

    float xr, xz, xn, nxr = 0.f, nxz = 0.f, nxn = 0.f;
    {
        long gb = rb0 * 3072 + e0 + e;
        xr = (float)gx[gb]; xz = (float)gx[gb + NI]; xn = (float)gx[gb + 2 * NI];
    }

    for (int t = 0; t < NT; ++t) {
        const half_t* hsrc = hf16 + (t & 1) * (NB * NI);
        i32x4 sv[8];
#pragma unroll
        for (int j = 0; j < 8; ++j) {
            int c = tid + 256 * j;             // 2048 chunks
            int lr = c >> 7, cin = c & 127;
            gload16_cc(sv[j], hsrc + (g * 16 + lr) * NI + cin * 8);
        }
        asm volatile("s_waitcnt vmcnt(0)" ::: "memory");
#pragma unroll
        for (int j = 0; j < 8; ++j) {
            int c = tid + 256 * j;
            int lr = c >> 7, cin = c & 127;
            *reinterpret_cast<i32x4*>(&hl[lr * NI + ((cin ^ (lr & 7)) << 3)]) = sv[j];
        }
        __syncthreads();

        if (t + 1 < NT) {                      // prefetch next gx
            long gb = (rb0 + t + 1) * 3072 + e0 + e;
            nxr = (float)gx[gb]; nxz = (float)gx[gb + NI]; nxn = (float)gx[gb + 2 * NI];
        }

        if (wv < 3) {
            f32x4 a0 = (f32x4){bgate, bgate, bgate, bgate};
            f32x4 a1 = (f32x4){0.f, 0.f, 0.f, 0.f};
#pragma unroll
            for (int ks = 0; ks < 32; ks += 2) {
                int ar = lane & 15;
                int br = wv * 16 + (lane & 15);
                int ao0 = ar * NI + ((ks * 32 + 8 * (lane >> 4)) ^ ((ar & 7) << 3));
                int bo0 = br * NI + ((ks * 32 + 8 * (lane >> 4)) ^ ((br & 7) << 3));
                int ao1 = ar * NI + (((ks + 1) * 32 + 8 * (lane >> 4)) ^ ((ar & 7) << 3));
                int bo1 = br * NI + (((ks + 1) * 32 + 8 * (lane >> 4)) ^ ((br & 7) << 3));
                a0 = __builtin_amdgcn_mfma_f32_16x16x32_f16(
                    *reinterpret_cast<const half8*>(&hl[ao0]),
                    *reinterpret_cast<const half8*>(&wl[bo0]), a0, 0, 0, 0);
                a1 = __builtin_amdgcn_mfma_f32_16x16x32_f16(
                    *reinterpret_cast<const half8*>(&hl[ao1]),
                    *reinterpret_cast<const half8*>(&wl[bo1]), a1, 0, 0, 0);
            }
            f32x4 acc = a0 + a1;
#pragma unroll
            for (int i = 0; i < 4; ++i)
                xch2[wv][4 * (lane >> 4) + i][lane & 15] = acc[i];
        }
        __syncthreads();

        float hn;
        {
            float r = 1.f / (1.f + __expf(-(xr + xch2[0][b][e])));
            float z = 1.f / (1.f + __expf(-(xz + xch2[1][b][e])));
            float n = tanhf(xn + r * xch2[2][b][e]);
            hn = (1.f - z) * n + z * hp;
            hp = hn;
            hst[b][e] = (half_t)hn;
        }
        __syncthreads();

        if (t + 1 < NT) {
            if (tid < 32) {
                int bb = tid >> 1, seg = tid & 1;
                i32x4 v = *reinterpret_cast<const i32x4*>(&hst[bb][seg * 8]);
                gstore16_cc(hf16 + ((t + 1) & 1) * (NB * NI) + (g * 16 + bb) * NI + e0 + seg * 8, v);
            }
            if (tid < 64) {
                asm volatile("s_waitcnt vmcnt(0)" ::: "memory");
                if (tid == 0) {
                    unsigned gv = t + 2;
                    asm volatile("global_store_dword %0, %1, off sc0 sc1"
                                 :: "v"(gslots + memb), "v"(gv) : "memory");
                }
            }
        }
        out[(rb0 + t) * NI + e0 + e] = hn;     // off the flag critical path
        if (t + 1 < NT) {
            if (tid < 64) {
                const unsigned* p = gslots + (tid & 63);
                int guard = 0;
                while (true) {
                    unsigned v;
                    asm volatile("global_load_dword %0, %1, off sc0 sc1"
                                 : "=v"(v) : "v"(p) : "memory");
                    asm volatile("s_waitcnt vmcnt(0)" ::: "memory");
                    if (__all(v >= (unsigned)(t + 2))) break;
                    __builtin_amdgcn_s_sleep(1);
                    if (++guard > (1 << 22)) break;
                }
            }
            __syncthreads();
        }
        xr = nxr; xz = nxz; xn = nxn;
    }
}

// ---------------- launcher ----------------
extern "C" void kernel_launch(void* const* d_in, const int* in_sizes, int n_in,
                              void* d_out, int out_size, void* d_ws, size_t ws_size,
                              hipStream_t stream) {
    const float* x     = (const float*)d_in[0];
    const float* w_ih1 = (const float*)d_in[1];
    const float* w_hh1 = (const float*)d_in[2];
    const float* b_ih1 = (const float*)d_in[3];
    const float* b_hh1 = (const float*)d_in[4];
    const float* w_ih2 = (const float*)d_in[5];
    const float* w_hh2 = (const float*)d_in[6];
    const float* b_ih2 = (const float*)d_in[7];
    const float* b_hh2 = (const float*)d_in[8];

    char* ws = (char*)d_ws;
    // layout (112 MB total; ws >= 151 MB proven in rounds 1/3):
    unsigned* slots1 = (unsigned*)ws;                  // [0, 2K)
    unsigned* slots2 = (unsigned*)(ws + 2048);         // [2K, 3K)
    half_t* h1f16  = (half_t*)(ws + 4096);             // 2 x 64x512 fp16 ping-pong
    half_t* h2f16  = (half_t*)(ws + 135168);           // 2 x 64x1024 fp16
    half_t* wih1h  = (half_t*)(ws + 1048576);          // 1536x1024
    half_t* whh1h  = (half_t*)(ws + 4194304);          // 1536x512
    half_t* wih2h  = (half_t*)(ws + 5767168);          // 3072x512
    half_t* whh2h  = (half_t*)(ws + 8912896);          // 3072x1024 -> ends 14.5MB
    half_t* gxU    = (half_t*)(ws + 16777216);         // [16MB, 112MB): [B][T][3072]
    float*  out    = (float*)d_out;

    hipMemsetAsync(ws, 0, 4096, stream);               // barrier slots = 0

    k_cvt<<<1536, 256, 0, stream>>>(w_ih1, wih1h, 393216);
    k_cvt<<<768,  256, 0, stream>>>(w_hh1, whh1h, 196608);
    k_cvt<<<1536, 256, 0, stream>>>(w_ih2, wih2h, 393216);
    k_cvt<<<3072, 256, 0, stream>>>(w_hh2, whh2h, 786432);

    // gx1 = x @ w_ih1^T + b_ih1, written into gxU cols [0,1536) with stride 3072
    k_gemm<1024, true><<<dim3(12, 128), 256, 0, stream>>>(x, wih1h, b_ih1, gxU, 1536, 3072);
    // layer-1 recurrence + fused gemm2 (gx2 overwrites gxU rows in place)
    k_phase1<<<256, 256, 0, stream>>>(whh1h, b_hh1, gxU, wih2h, b_ih2, gxU, h1f16, slots1);
    // layer-2 recurrence -> out (fp32)
    k_phase2<<<256, 256, 0, stream>>>(whh2h, b_hh2, gxU, out, h2f16, slots2);
}

// Round 5
// 2533.004 us; speedup vs baseline: 1.0687x; 1.0687x over previous
//
#include <hip/hip_runtime.h>

typedef _Float16 half_t;
typedef _Float16 half8  __attribute__((ext_vector_type(8)));
typedef float    f32x4  __attribute__((ext_vector_type(4)));
typedef int      i32x4  __attribute__((ext_vector_type(4)));

#define NB 64
#define NT 256
#define NI 1024
#define NH 512

// ---- cache-bypassing (MALL-coherent) 16B load/store ----
__device__ __forceinline__ void gload16_cc(i32x4& v, const void* p) {
    asm volatile("global_load_dwordx4 %0, %1, off sc0 sc1"
                 : "=v"(v) : "v"(p) : "memory");
}
__device__ __forceinline__ void gstore16_cc(void* p, i32x4 v) {
    asm volatile("global_store_dwordx4 %0, %1, off sc0 sc1"
                 :: "v"(p), "v"(v) : "memory");
}

// ---------------- flag-array group barrier ----------------
// slots[i] = generation WG i has arrived at (monotone). Wave 0 drains its own
// global stores, leader stores its slot, all lanes busy-poll all slots
// wave-wide (no s_sleep: detect period = one MALL round-trip).
__device__ __forceinline__ void flag_barrier(unsigned* slots, int nslots,
                                             int my, unsigned gen, int tid) {
    if (tid < 64) {
        asm volatile("s_waitcnt vmcnt(0)" ::: "memory");   // h stores visible first
        if (tid == 0) {
            unsigned gv = gen;
            asm volatile("global_store_dword %0, %1, off sc0 sc1"
                         :: "v"(slots + my), "v"(gv) : "memory");
        }
        const unsigned* p = slots + (tid & (nslots - 1));
        int guard = 0;
        while (true) {
            unsigned v;
            asm volatile("global_load_dword %0, %1, off sc0 sc1"
                         : "=v"(v) : "v"(p) : "memory");
            asm volatile("s_waitcnt vmcnt(0)" ::: "memory");
            if (__all(v >= gen)) break;
            if (++guard > (1 << 24)) break;   // failsafe: wrong beats hang
        }
    }
    __syncthreads();
}

// ---------------- fp32 -> fp16 convert ----------------
__global__ __launch_bounds__(256) void k_cvt(const float* __restrict__ s,
                                             half_t* __restrict__ d, int n4) {
    int i = blockIdx.x * 256 + threadIdx.x;
    if (i < n4) {
        float4 v = reinterpret_cast<const float4*>(s)[i];
        half_t h4[4] = {(half_t)v.x, (half_t)v.y, (half_t)v.z, (half_t)v.w};
        *reinterpret_cast<long*>(&d[i * 4]) = *reinterpret_cast<long*>(h4);
    }
}

// ---------------- GEMM: C[M,N](f16) = A[M,K] * Bw[N,K]^T + bias ----------------
// A is fp32 (AF32, converted during staging) or fp16. C row stride = ldc.
template <int K, bool AF32>
__global__ __launch_bounds__(256) void k_gemm(const void* __restrict__ Av,
                                              const half_t* __restrict__ Bw,
                                              const float* __restrict__ bias,
                                              half_t* __restrict__ C, int N, int ldc) {
    constexpr int BK = 64;
    __shared__ half_t Al[2][128 * BK] __attribute__((aligned(16)));
    __shared__ half_t Bl[2][128 * BK] __attribute__((aligned(16)));

    const int tid = threadIdx.x, lane = tid & 63, wv = tid >> 6;
    const long m0 = (long)blockIdx.y * 128;
    const long n0 = (long)blockIdx.x * 128;
    const int wm = (wv >> 1) * 64, wn = (wv & 1) * 64;

    f32x4 acc[4][4];
#pragma unroll
    for (int nt = 0; nt < 4; ++nt) {
        float bv = bias[n0 + wn + nt * 16 + (lane & 15)];
#pragma unroll
        for (int mt = 0; mt < 4; ++mt) acc[mt][nt] = (f32x4){bv, bv, bv, bv};
    }

    auto stage = [&](int buf, int kt) {
#pragma unroll
        for (int j = 0; j < 4; ++j) {
            int c = tid + 256 * j;
            int row = c >> 3, cin = c & 7;
            int dst = row * BK + ((cin ^ (row & 7)) << 3);
            if constexpr (AF32) {
                const float* Af = (const float*)Av;
                const float* src = Af + (m0 + row) * K + kt * BK + cin * 8;
                float4 f0 = *reinterpret_cast<const float4*>(src);
                float4 f1 = *reinterpret_cast<const float4*>(src + 4);
                half8 h;
                h[0] = (half_t)f0.x; h[1] = (half_t)f0.y; h[2] = (half_t)f0.z; h[3] = (half_t)f0.w;
                h[4] = (half_t)f1.x; h[5] = (half_t)f1.y; h[6] = (half_t)f1.z; h[7] = (half_t)f1.w;
                *reinterpret_cast<half8*>(&Al[buf][dst]) = h;
            } else {
                const half_t* Ah = (const half_t*)Av;
                *reinterpret_cast<int4*>(&Al[buf][dst]) =
                    *reinterpret_cast<const int4*>(Ah + (m0 + row) * K + kt * BK + cin * 8);
            }
            *reinterpret_cast<int4*>(&Bl[buf][dst]) =
                *reinterpret_cast<const int4*>(Bw + (n0 + row) * K + kt * BK + cin * 8);
        }
    };

    stage(0, 0);
    __syncthreads();
    constexpr int NK = K / BK;
    int buf = 0;
    for (int kt = 0; kt < NK; ++kt) {
        if (kt + 1 < NK) stage(buf ^ 1, kt + 1);
        half8 af[4][2], bf[4][2];
#pragma unroll
        for (int mt = 0; mt < 4; ++mt)
#pragma unroll
            for (int ks = 0; ks < 2; ++ks) {
                int lr = wm + mt * 16 + (lane & 15);
                int off = lr * BK + ((ks * 32 + 8 * (lane >> 4)) ^ ((lr & 7) << 3));
                af[mt][ks] = *reinterpret_cast<const half8*>(&Al[buf][off]);
            }
#pragma unroll
        for (int nt = 0; nt < 4; ++nt)
#pragma unroll
            for (int ks = 0; ks < 2; ++ks) {
                int lr = wn + nt * 16 + (lane & 15);
                int off = lr * BK + ((ks * 32 + 8 * (lane >> 4)) ^ ((lr & 7) << 3));
                bf[nt][ks] = *reinterpret_cast<const half8*>(&Bl[buf][off]);
            }
#pragma unroll
        for (int mt = 0; mt < 4; ++mt)
#pragma unroll
            for (int nt = 0; nt < 4; ++nt)
#pragma unroll
                for (int ks = 0; ks < 2; ++ks)
                    acc[mt][nt] = __builtin_amdgcn_mfma_f32_16x16x32_f16(
                        af[mt][ks], bf[nt][ks], acc[mt][nt], 0, 0, 0);
        __syncthreads();
        buf ^= 1;
    }
#pragma unroll
    for (int mt = 0; mt < 4; ++mt)
#pragma unroll
        for (int nt = 0; nt < 4; ++nt)
#pragma unroll
            for (int i = 0; i < 4; ++i) {
                long row = m0 + wm + mt * 16 + 4 * (lane >> 4) + i;
                long col = n0 + wn + nt * 16 + (lane & 15);
                C[row * (long)ldc + col] = (half_t)acc[mt][nt][i];
            }
}

// ---------------- Phase 1: layer-1 recurrence (persistent) ----------------
// 8 groups x 32 WGs; group g owns batches [8g,8g+8). WG owns 16 h-elems.
// hrelu store for step t-1 is deferred to the top of step t so it drains in
// the h-load vmcnt(0) -- off the flag critical path.
__global__ __launch_bounds__(256, 1) void k_phase1(const half_t* __restrict__ whh,
                                                   const float* __restrict__ bhh,
                                                   const half_t* __restrict__ gx,
                                                   half_t* __restrict__ hrelu,
                                                   half_t* __restrict__ hf16,
                                                   unsigned* __restrict__ slots) {
    __shared__ half_t wl[48 * NH] __attribute__((aligned(16)));   // 48KB
    __shared__ half_t hl[16 * NH] __attribute__((aligned(16)));   // 16KB
    __shared__ float xch[3][8][16];
    __shared__ half_t hst[8][16] __attribute__((aligned(16)));

    const int tid = threadIdx.x, lane = tid & 63, wv = tid >> 6;
    const int g = blockIdx.x & 7, memb = blockIdx.x >> 3;
    const int e0 = memb * 16;
    unsigned* gslots = slots + g * 64;

    // gate weights: local row lr = 16*gate + e -> global row gate*512 + e0 + e
#pragma unroll
    for (int j = 0; j < 12; ++j) {
        int c = tid + 256 * j;                 // 3072 chunks
        int lr = c >> 6, cin = c & 63;
        int grow = (lr >> 4) * NH + e0 + (lr & 15);
        int dst = lr * NH + ((cin ^ (lr & 7)) << 3);
        *reinterpret_cast<int4*>(&wl[dst]) =
            *reinterpret_cast<const int4*>(whh + (long)grow * NH + cin * 8);
    }
    // zero A-tile pad rows 8..15 (stay zero forever)
#pragma unroll
    for (int j = 0; j < 2; ++j) {
        int c = tid + 256 * j;
        int lr = 8 + (c >> 6), cin = c & 63;
        int4 z; z.x = z.y = z.z = z.w = 0;
        *reinterpret_cast<int4*>(&hl[lr * NH + cin * 8]) = z;
    }
    // zero initial h (buffer 0) for this WG's slice
    if (tid < 16) {
        i32x4 z = (i32x4){0, 0, 0, 0};
        int bb = tid >> 1, seg = tid & 1;
        gstore16_cc(hf16 + (g * 8 + bb) * NH + e0 + seg * 8, z);
    }
    float hp = 0.f, hrp = 0.f;                 // register-resident h / relu(h)
    __syncthreads();
    flag_barrier(gslots, 32, memb, 1, tid);

    const float bgate = (wv < 3) ? bhh[wv * NH + e0 + (lane & 15)] : 0.f;
    const int b = tid >> 4, e = tid & 15;
    const long rb0 = (long)(g * 8 + b) * NT;

    float xr = 0.f, xz = 0.f, xn = 0.f, nxr = 0.f, nxz = 0.f, nxn = 0.f;
    if (tid < 128) {                           // gx for t=0 (stride 1536)
        long gb = rb0 * 1536 + e0 + e;
        xr = (float)gx[gb]; xz = (float)gx[gb + NH]; xn = (float)gx[gb + 2 * NH];
    }

    for (int t = 0; t < NT; ++t) {
        // deferred hrelu store for t-1 (drains with the h loads below)
        if (tid < 128 && t > 0)
            hrelu[(rb0 + t - 1) * NH + e0 + e] = (half_t)hrp;

        const half_t* hsrc = hf16 + (t & 1) * (NB * NH);
        i32x4 sv[2];
#pragma unroll
        for (int j = 0; j < 2; ++j) {
            int c = tid + 256 * j;             // 512 chunks
            int lr = c >> 6, cin = c & 63;
            gload16_cc(sv[j], hsrc + (g * 8 + lr) * NH + cin * 8);
        }
        asm volatile("s_waitcnt vmcnt(0)" ::: "memory");
#pragma unroll
        for (int j = 0; j < 2; ++j) {
            int c = tid + 256 * j;
            int lr = c >> 6, cin = c & 63;
            *reinterpret_cast<i32x4*>(&hl[lr * NH + ((cin ^ (lr & 7)) << 3)]) = sv[j];
        }
        __syncthreads();

        // prefetch next step's gx (hidden under MFMA + barrier)
        if (tid < 128 && t + 1 < NT) {
            long gb = (rb0 + t + 1) * 1536 + e0 + e;
            nxr = (float)gx[gb]; nxz = (float)gx[gb + NH]; nxn = (float)gx[gb + 2 * NH];
        }

        if (wv < 3) {                          // wave wv computes gate wv
            f32x4 a0 = (f32x4){bgate, bgate, bgate, bgate};
            f32x4 a1 = (f32x4){0.f, 0.f, 0.f, 0.f};
#pragma unroll
            for (int ks = 0; ks < 16; ks += 2) {
                int ar = lane & 15;
                int br = wv * 16 + (lane & 15);
                int ao0 = ar * NH + ((ks * 32 + 8 * (lane >> 4)) ^ ((ar & 7) << 3));
                int bo0 = br * NH + ((ks * 32 + 8 * (lane >> 4)) ^ ((br & 7) << 3));
                int ao1 = ar * NH + (((ks + 1) * 32 + 8 * (lane >> 4)) ^ ((ar & 7) << 3));
                int bo1 = br * NH + (((ks + 1) * 32 + 8 * (lane >> 4)) ^ ((br & 7) << 3));
                a0 = __builtin_amdgcn_mfma_f32_16x16x32_f16(
                    *reinterpret_cast<const half8*>(&hl[ao0]),
                    *reinterpret_cast<const half8*>(&wl[bo0]), a0, 0, 0, 0);
                a1 = __builtin_amdgcn_mfma_f32_16x16x32_f16(
                    *reinterpret_cast<const half8*>(&hl[ao1]),
                    *reinterpret_cast<const half8*>(&wl[bo1]), a1, 0, 0, 0);
            }
            f32x4 acc = a0 + a1;
            if (lane < 32) {
#pragma unroll
                for (int i = 0; i < 4; ++i)
                    xch[wv][4 * (lane >> 4) + i][lane & 15] = acc[i];
            }
        }
        __syncthreads();

        if (tid < 128) {                       // gate combine, one thread per (b,e)
            float r = 1.f / (1.f + __expf(-(xr + xch[0][b][e])));
            float z = 1.f / (1.f + __expf(-(xz + xch[1][b][e])));
            float n = tanhf(xn + r * xch[2][b][e]);
            float hn = (1.f - z) * n + z * hp;
            hp = hn;
            hrp = fmaxf(hn, 0.f);
            hst[b][e] = (half_t)hn;
        }
        __syncthreads();

        if (t + 1 < NT) {
            if (tid < 16) {
                int bb = tid >> 1, seg = tid & 1;
                i32x4 v = *reinterpret_cast<const i32x4*>(&hst[bb][seg * 8]);
                gstore16_cc(hf16 + ((t + 1) & 1) * (NB * NH) + (g * 8 + bb) * NH + e0 + seg * 8, v);
            }
            flag_barrier(gslots, 32, memb, t + 2, tid);
        }
        xr = nxr; xz = nxz; xn = nxn;
    }
    // final hrelu store (t = NT-1)
    if (tid < 128)
        hrelu[(rb0 + NT - 1) * NH + e0 + e] = (half_t)hrp;
}

// ---------------- Phase 2: layer-2 recurrence (persistent) ----------------
// 4 groups x 64 WGs; group g owns batches [16g,16g+16). WG owns 16 out-elems.
// out store for step t-1 deferred to the top of step t (drains with h loads).
__global__ __launch_bounds__(256, 1) void k_phase2(const half_t* __restrict__ whh,
                                                   const float* __restrict__ bhh,
                                                   const half_t* __restrict__ gx,
                                                   float* __restrict__ out,
                                                   half_t* __restrict__ hf16,
                                                   unsigned* __restrict__ slots) {
    __shared__ half_t wl[48 * NI] __attribute__((aligned(16)));   // 96KB
    __shared__ half_t hl[16 * NI] __attribute__((aligned(16)));   // 32KB
    __shared__ float xch2[3][16][16];
    __shared__ half_t hst[16][16] __attribute__((aligned(16)));

    const int tid = threadIdx.x, lane = tid & 63, wv = tid >> 6;
    const int xcd = blockIdx.x & 7;
    const int g = xcd >> 1;
    const int memb = ((blockIdx.x >> 3) << 1) | (xcd & 1);  // 0..63
    const int e0 = memb * 16;
    unsigned* gslots = slots + g * 64;

#pragma unroll
    for (int j = 0; j < 24; ++j) {
        int c = tid + 256 * j;                 // 6144 chunks
        int lr = c >> 7, cin = c & 127;
        int grow = (lr >> 4) * NI + e0 + (lr & 15);
        int dst = lr * NI + ((cin ^ (lr & 7)) << 3);
        *reinterpret_cast<int4*>(&wl[dst]) =
            *reinterpret_cast<const int4*>(whh + (long)grow * NI + cin * 8);
    }
    if (tid < 32) {
        i32x4 z = (i32x4){0, 0, 0, 0};
        int bb = tid >> 1, seg = tid & 1;
        gstore16_cc(hf16 + (g * 16 + bb) * NI + e0 + seg * 8, z);
    }
    float hp = 0.f;
    __syncthreads();
    flag_barrier(gslots, 64, memb, 1, tid);

    const float bgate = (wv < 3) ? bhh[wv * NI + e0 + (lane & 15)] : 0.f;
    const int b = tid >> 4, e = tid & 15;
    const long rb0 = (long)(g * 16 + b) * NT;

    float xr, xz, xn, nxr = 0.f, nxz = 0.f, nxn = 0.f;
    {
        long gb = rb0 * 3072 + e0 + e;
        xr = (float)gx[gb]; xz = (float)gx[gb + NI]; xn = (float)gx[gb + 2 * NI];
    }

    for (int t = 0; t < NT; ++t) {
        // deferred out store for t-1 (drains with the h loads below)
        if (t > 0)
            out[(rb0 + t - 1) * NI + e0 + e] = hp;

        const half_t* hsrc = hf16 + (t & 1) * (NB * NI);
        i32x4 sv[8];
#pragma unroll
        for (int j = 0; j < 8; ++j) {
            int c = tid + 256 * j;             // 2048 chunks
            int lr = c >> 7, cin = c & 127;
            gload16_cc(sv[j], hsrc + (g * 16 + lr) * NI + cin * 8);
        }
        asm volatile("s_waitcnt vmcnt(0)" ::: "memory");
#pragma unroll
        for (int j = 0; j < 8; ++j) {
            int c = tid + 256 * j;
            int lr = c >> 7, cin = c & 127;
            *reinterpret_cast<i32x4*>(&hl[lr * NI + ((cin ^ (lr & 7)) << 3)]) = sv[j];
        }
        __syncthreads();

        if (t + 1 < NT) {                      // prefetch next gx
            long gb = (rb0 + t + 1) * 3072 + e0 + e;
            nxr = (float)gx[gb]; nxz = (float)gx[gb + NI]; nxn = (float)gx[gb + 2 * NI];
        }

        if (wv < 3) {
            f32x4 a0 = (f32x4){bgate, bgate, bgate, bgate};
            f32x4 a1 = (f32x4){0.f, 0.f, 0.f, 0.f};
#pragma unroll
            for (int ks = 0; ks < 32; ks += 2) {
                int ar = lane & 15;
                int br = wv * 16 + (lane & 15);
                int ao0 = ar * NI + ((ks * 32 + 8 * (lane >> 4)) ^ ((ar & 7) << 3));
                int bo0 = br * NI + ((ks * 32 + 8 * (lane >> 4)) ^ ((br & 7) << 3));
                int ao1 = ar * NI + (((ks + 1) * 32 + 8 * (lane >> 4)) ^ ((ar & 7) << 3));
                int bo1 = br * NI + (((ks + 1) * 32 + 8 * (lane >> 4)) ^ ((br & 7) << 3));
                a0 = __builtin_amdgcn_mfma_f32_16x16x32_f16(
                    *reinterpret_cast<const half8*>(&hl[ao0]),
                    *reinterpret_cast<const half8*>(&wl[bo0]), a0, 0, 0, 0);
                a1 = __builtin_amdgcn_mfma_f32_16x16x32_f16(
                    *reinterpret_cast<const half8*>(&hl[ao1]),
                    *reinterpret_cast<const half8*>(&wl[bo1]), a1, 0, 0, 0);
            }
            f32x4 acc = a0 + a1;
#pragma unroll
            for (int i = 0; i < 4; ++i)
                xch2[wv][4 * (lane >> 4) + i][lane & 15] = acc[i];
        }
        __syncthreads();

        {
            float r = 1.f / (1.f + __expf(-(xr + xch2[0][b][e])));
            float z = 1.f / (1.f + __expf(-(xz + xch2[1][b][e])));
            float n = tanhf(xn + r * xch2[2][b][e]);
            float hn = (1.f - z) * n + z * hp;
            hp = hn;
            hst[b][e] = (half_t)hn;
        }
        __syncthreads();

        if (t + 1 < NT) {
            if (tid < 32) {
                int bb = tid >> 1, seg = tid & 1;
                i32x4 v = *reinterpret_cast<const i32x4*>(&hst[bb][seg * 8]);
                gstore16_cc(hf16 + ((t + 1) & 1) * (NB * NI) + (g * 16 + bb) * NI + e0 + seg * 8, v);
            }
            flag_barrier(gslots, 64, memb, t + 2, tid);
        }
        xr = nxr; xz = nxz; xn = nxn;
    }
    // final out store (t = NT-1)
    out[(rb0 + NT - 1) * NI + e0 + e] = hp;
}

// ---------------- launcher ----------------
extern "C" void kernel_launch(void* const* d_in, const int* in_sizes, int n_in,
                              void* d_out, int out_size, void* d_ws, size_t ws_size,
                              hipStream_t stream) {
    const float* x     = (const float*)d_in[0];
    const float* w_ih1 = (const float*)d_in[1];
    const float* w_hh1 = (const float*)d_in[2];
    const float* b_ih1 = (const float*)d_in[3];
    const float* b_hh1 = (const float*)d_in[4];
    const float* w_ih2 = (const float*)d_in[5];
    const float* w_hh2 = (const float*)d_in[6];
    const float* b_ih2 = (const float*)d_in[7];
    const float* b_hh2 = (const float*)d_in[8];

    char* ws = (char*)d_ws;
    // layout (ends at 144MB; ws >= 151MB proven in rounds 1/3):
    unsigned* slots1 = (unsigned*)ws;                  // [0, 2K)
    unsigned* slots2 = (unsigned*)(ws + 2048);         // [2K, 3K)
    half_t* h1f16  = (half_t*)(ws + 4096);             // 2 x 64x512 fp16 ping-pong
    half_t* h2f16  = (half_t*)(ws + 135168);           // 2 x 64x1024 fp16
    half_t* wih1h  = (half_t*)(ws + 1048576);          // 1536x1024
    half_t* whh1h  = (half_t*)(ws + 4194304);          // 1536x512
    half_t* wih2h  = (half_t*)(ws + 5767168);          // 3072x512
    half_t* whh2h  = (half_t*)(ws + 8912896);          // 3072x1024 -> ends 14.9MB
    half_t* hrelu  = (half_t*)(ws + 16777216);         // [16,32)MB: [B][T][512] f16
    half_t* gxU    = (half_t*)(ws + 50331648);         // [48,144)MB: gx1 then gx2
    float*  out    = (float*)d_out;

    hipMemsetAsync(ws, 0, 4096, stream);               // barrier slots = 0

    k_cvt<<<1536, 256, 0, stream>>>(w_ih1, wih1h, 393216);
    k_cvt<<<768,  256, 0, stream>>>(w_hh1, whh1h, 196608);
    k_cvt<<<1536, 256, 0, stream>>>(w_ih2, wih2h, 393216);
    k_cvt<<<3072, 256, 0, stream>>>(w_hh2, whh2h, 786432);

    // gx1 = x @ w_ih1^T + b_ih1   [16384 x 1536], K=1024 (A fp32, converted in-stage)
    k_gemm<1024, true><<<dim3(12, 128), 256, 0, stream>>>(x, wih1h, b_ih1, gxU, 1536, 1536);
    // layer-1 recurrence -> hrelu
    k_phase1<<<256, 256, 0, stream>>>(whh1h, b_hh1, gxU, hrelu, h1f16, slots1);
    // gx2 = relu(h1) @ w_ih2^T + b_ih2   [16384 x 3072], K=512 (overwrites gx1, now dead)
    k_gemm<512, false><<<dim3(24, 128), 256, 0, stream>>>(hrelu, wih2h, b_ih2, gxU, 3072, 3072);
    // layer-2 recurrence -> out (fp32)
    k_phase2<<<256, 256, 0, stream>>>(whh2h, b_hh2, gxU, out, h2f16, slots2);
}